// Round 15
// baseline (146.452 us; speedup 1.0000x reference)
//
#include <hip/hip_runtime.h>

#define BB 4
#define NN 2048
#define INF 256
#define HH 8
#define DD 32
#define LOG2E 1.4426950408889634f

typedef __attribute__((ext_vector_type(8))) _Float16 half8;
typedef __attribute__((ext_vector_type(8))) short short8;
typedef __attribute__((ext_vector_type(2))) _Float16 h2;
typedef __attribute__((ext_vector_type(4))) float f32x4;
typedef __attribute__((address_space(3))) unsigned as3_u32;
typedef __attribute__((address_space(1))) const unsigned as1_u32;

__device__ __forceinline__ unsigned short f16u(float v) {
    union { _Float16 f; unsigned short u; } c;
    c.f = (_Float16)v;
    return c.u;
}

// adjprep: zero-LDS. bid<2048: adjbits (1 row/wave, 32 loads in flight, ballots
// on regs, one coalesced 256B store). bid>=2048 (32 blocks): wprep — wTf16
// [h*32+d][f] f16 transpose of W (computed once, not per-whk-block) + we dots.
__global__ __launch_bounds__(256) void adjprep_kernel(
    const int* __restrict__ adj, const float* __restrict__ W,
    const float* __restrict__ a, unsigned* __restrict__ bitsG,
    float* __restrict__ we_g, unsigned short* __restrict__ wTf16)
{
    const int bid = blockIdx.x, t = threadIdx.x;
    if (bid < 2048) {
        const int wv = t >> 6, l = t & 63;
        const int row = bid * 4 + wv;                   // global (b*N + i) row
        const int* ap = adj + (size_t)row * NN;
        int vreg[32];
        #pragma unroll
        for (int c = 0; c < 32; ++c) vreg[c] = ap[c * 64 + l];   // 32 in flight
        unsigned myw = 0;
        #pragma unroll
        for (int c = 0; c < 32; ++c) {
            unsigned long long m = __ballot(vreg[c] != 0);
            unsigned sel = (l & 1) ? (unsigned)(m >> 32) : (unsigned)m;
            myw = ((l >> 1) == c) ? sel : myw;
        }
        bitsG[(size_t)row * 64 + l] = myw;              // 256B coalesced
        return;
    }
    const int k = bid - 2048;                           // 0..31
    if (k < 16) {                                       // we part
        const int h = k & 7, sel = k >> 3;
        const float* wr = W + ((size_t)(h * INF + t)) * DD;
        const float* av = a + h * 2 * DD + sel * DD;
        float acc = 0.f;
        #pragma unroll
        for (int d = 0; d < DD; ++d) acc += wr[d] * av[d];
        we_g[k * INF + t] = acc * LOG2E;
    }
    #pragma unroll
    for (int r2 = 0; r2 < 8; ++r2) {                    // wT rows k*8 .. k*8+8
        int row = k * 8 + r2;
        int h = row >> 5, d = row & 31;
        wTf16[row * INF + t] = f16u(W[((size_t)(h * INF + t)) * DD + d]);
    }
}

// prepw: role = bid&1.
// role0 (512): whk GEMM — x staged coalesced->f16 LDS; wb staged from wTf16
//   (coalesced short8, no per-block transpose). -> whT2 f16 [bh][j/8][d][8].
// role1 (512): ek — xs+weld2 staged; -> esrc (log2 fp32) + ejE/ejF f16 pairs.
__global__ __launch_bounds__(256) void prepw_kernel(
    const float* __restrict__ x, const unsigned short* __restrict__ wTf16,
    const float* __restrict__ we_g, unsigned short* __restrict__ whT2,
    float* __restrict__ esrc, unsigned* __restrict__ ejE,
    unsigned* __restrict__ ejF)
{
    __shared__ __align__(16) unsigned short smem[64 * 264 * 2];
    const int bid = blockIdx.x, t = threadIdx.x;
    const int role = bid & 1, id = bid >> 1;

    if (role == 0) {                       // ---- whk ----
        unsigned short* xb = smem;                       // [64][264] f16
        unsigned short* wb = smem + 64 * 264;            // [64][264] f16
        const int hp = id & 3, tl = (id >> 2) & 31, b = id >> 7;
        const int n0 = tl * 64;

        #pragma unroll
        for (int p = 0; p < 16; ++p) {                   // x tile -> f16 LDS
            int flat = p * 1024 + t * 4;
            int row = flat >> 8, col = flat & 255;
            f32x4 g = *(const f32x4*)&x[((size_t)(b * NN + n0 + row)) * INF + col];
            union { h2 h; unsigned u; } c0, c1;
            c0.h = (h2){(_Float16)g[0], (_Float16)g[1]};
            c1.h = (h2){(_Float16)g[2], (_Float16)g[3]};
            uint2 pk; pk.x = c0.u; pk.y = c1.u;
            *(uint2*)&xb[row * 264 + col] = pk;
        }
        #pragma unroll
        for (int p = 0; p < 8; ++p) {                    // wb from wTf16: coalesced
            int flat = p * 2048 + t * 8;                 // 8 halfs (16B) per thread
            int row = flat >> 8, col = flat & 255;
            short8 v = *(const short8*)&wTf16[(size_t)(hp * 64 + row) * INF + col];
            *(short8*)&wb[row * 264 + col] = v;
        }
        __syncthreads();

        const int w = t >> 6, l = t & 63;
        const int ml = l & 15, q = l >> 4;
        f32x4 acc[4] = {};
        const unsigned short* apx = &xb[(w * 16 + ml) * 264 + q * 8];
        #pragma unroll
        for (int k0 = 0; k0 < INF; k0 += 32) {
            half8 A = *(const half8*)&apx[k0];
            #pragma unroll
            for (int c16 = 0; c16 < 4; ++c16) {
                half8 Bf = *(const half8*)&wb[(c16 * 16 + ml) * 264 + q * 8 + k0];
                acc[c16] = __builtin_amdgcn_mfma_f32_16x16x32_f16(A, Bf, acc[c16], 0, 0, 0);
            }
        }
        __syncthreads();
        unsigned short* ldsC = xb;                       // [64 col][72 row]
        #pragma unroll
        for (int c16 = 0; c16 < 4; ++c16)
            #pragma unroll
            for (int r = 0; r < 4; ++r) {
                int col = c16 * 16 + ml;
                int rt  = w * 16 + q * 4 + r;
                ldsC[col * 72 + rt] = f16u(acc[c16][r]);
            }
        __syncthreads();
        #pragma unroll
        for (int p = 0; p < 2; ++p) {
            int g = p * 256 + t;
            int d = g & 31, jo = (g >> 5) & 7, hh = g >> 8;
            half8 vv = *(const half8*)&ldsC[(hh * 32 + d) * 72 + jo * 8];
            int bh = b * 8 + hp * 2 + hh;
            *(half8*)&whT2[(((size_t)bh * 256 + tl * 8 + jo) * 32 + d) * 8] = vv;
        }
        return;
    }

    // ---- ek ----
    float* xs    = (float*)smem;                         // [16][260]
    float* weld2 = (float*)smem + 16 * 260;              // [c=f>>4][k*16+fi]
    const int tile = id & 127, b = id >> 7;
    const int n0 = tile * 16;

    #pragma unroll
    for (int p = 0; p < 4; ++p) {
        int flat = p * 1024 + t * 4;
        int row = flat >> 8, col = flat & 255;
        f32x4 g = *(const f32x4*)&x[((size_t)(b * NN + n0 + row)) * INF + col];
        *(f32x4*)&xs[row * 260 + col] = g;
    }
    #pragma unroll
    for (int p = 0; p < 4; ++p) {                        // we_g: 4096 floats
        int flat = p * 1024 + t * 4;
        int k = flat >> 8, f = flat & 255;
        f32x4 g = *(const f32x4*)&we_g[flat];
        *(f32x4*)&weld2[(f >> 4) * 260 + k * 16 + (f & 15)] = g;
    }
    __syncthreads();

    const int row = t >> 4, cc = t & 15;
    f32x4 xv[4];
    #pragma unroll
    for (int i = 0; i < 4; ++i)
        xv[i] = *(const f32x4*)&xs[row * 260 + cc * 16 + i * 4];

    float keep = 0.f;
    #pragma unroll
    for (int k = 0; k < 16; ++k) {
        float s = 0.f;
        #pragma unroll
        for (int i = 0; i < 4; ++i) {
            f32x4 w4 = *(const f32x4*)&weld2[cc * 260 + k * 16 + i * 4];
            s += xv[i][0]*w4[0] + xv[i][1]*w4[1] + xv[i][2]*w4[2] + xv[i][3]*w4[3];
        }
        s += __shfl_xor(s, 1, 64);
        s += __shfl_xor(s, 2, 64);
        s += __shfl_xor(s, 4, 64);
        s += __shfl_xor(s, 8, 64);
        keep = (cc == k) ? s : keep;
    }
    const int n = n0 + row;
    // all lanes compute + shfl (uniform exec); only cc>=8 even rows store
    float Ej = __builtin_amdgcn_exp2f(keep);
    float Fj = __builtin_amdgcn_exp2f(0.2f * keep);
    unsigned eh = (unsigned)f16u(Ej);
    unsigned fh = (unsigned)f16u(Fj);
    unsigned eo = (unsigned)__shfl_xor((int)eh, 16, 64);  // partner row (n^1)
    unsigned fo = (unsigned)__shfl_xor((int)fh, 16, 64);
    if (cc < 8) {
        esrc[(b * 8 + cc) * NN + n] = keep;
    } else if (!(row & 1)) {
        int bh = b * 8 + (cc - 8);
        ejE[bh * 1024 + n / 2] = (eo << 16) | eh;
        ejF[bh * 1024 + n / 2] = (fo << 16) | fh;
    }
}

// attn: 1024 blocks x 512 thr; 8 waves = 4 row-waves x 2 j-halves (js).
// Wave = 16 rows x 1024 j (8 chunk-iters). Per iter: stage whb chunk (2x8KB,
// dbuf, global_load_lds), 1 barrier; E/F pairs read DIRECT from L2 (256KB
// resident, 16-lane-uniform uint4 broadcast) — no eps LDS round-trip.
// Packed-f16 score: p_pair = pk_max(pk_mul(F,Gi2),E) & mask32 — 6 VALU/2 ent.
// Gi = 2^(-0.8 ei): per-row scale cancels in softmax. Combine js at the end.
__global__ __launch_bounds__(512, 8) void attn_kernel(
    const unsigned short* __restrict__ whT2, const float* __restrict__ esrc,
    const unsigned* __restrict__ ejE, const unsigned* __restrict__ ejF,
    const unsigned* __restrict__ bitsG, float* __restrict__ out)
{
    __shared__ __align__(16) unsigned short whs[2][2][4096];  // [buf][js][8KB]
    const int t = threadIdx.x, w = t >> 6, l = t & 63;
    const int rw = w & 3, js = w >> 2;
    const int ml = l & 15, q = l >> 4;
    const int obid = blockIdx.x;
    const int bid = (obid & 7) * 128 + (obid >> 3);         // XCD swizzle (1024=8*128)
    const int ig = bid & 31, h = (bid >> 5) & 7, b = bid >> 8;
    const int bh = b * HH + h;
    const int i0 = ig * 64 + rw * 16;                       // wave's 16 rows

    const float ei = esrc[bh * NN + i0 + ml];
    const float Gi = __builtin_amdgcn_exp2f(-0.8f * ei);
    const h2 gi2 = {(_Float16)Gi, (_Float16)Gi};

    const unsigned short* whb = whT2 + (size_t)bh * (256 * 256);  // [jg][d][8]
    const unsigned* epE = ejE + bh * 1024 + js * 512;
    const unsigned* epF = ejF + bh * 1024 + js * 512;
    const unsigned* mbase = bitsG + ((size_t)(b * NN + i0 + ml)) * 64 + js * 32;

    auto stage = [&](int it, int buf) {
        // this js-group's chunk (js*8+it): 8KB; wave rw stages bytes rw*2048..+2048
        const char* g = (const char*)whb + (js * 8 + it) * 8192 + rw * 2048 + l * 16;
        unsigned short* ld = &whs[buf][js][rw * 1024];        // wave-uniform base
        __builtin_amdgcn_global_load_lds((as1_u32*)g, (as3_u32*)ld, 16, 0, 0);
        __builtin_amdgcn_global_load_lds((as1_u32*)(g + 1024), (as3_u32*)(ld + 512), 16, 0, 0);
    };

    const half8 hones = {(_Float16)1.f, (_Float16)1.f, (_Float16)1.f, (_Float16)1.f,
                         (_Float16)1.f, (_Float16)1.f, (_Float16)1.f, (_Float16)1.f};
    f32x4 accP = {}, accQ = {}, accD = {};

    stage(0, 0);
    uint4 mrow = *(const uint4*)&mbase[0];
    for (int it = 0; it < 8; ++it) {
        __syncthreads();                  // stage(it) complete; buf^1 free
        if (it < 7) stage(it + 1, (it + 1) & 1);
        const int buf = it & 1;
        const uint4 mcur = mrow;
        if (it < 7) mrow = *(const uint4*)&mbase[(it + 1) * 4];  // prefetch
        const unsigned mw[4] = {mcur.x, mcur.y, mcur.z, mcur.w};
        const unsigned* epc = epE + it * 64 + q * 4;
        const unsigned* fpc = epF + it * 64 + q * 4;
        #pragma unroll
        for (int k = 0; k < 4; ++k) {
            const unsigned short* wp = &whs[buf][js][(k * 4 + q) * 256];
            half8 B0 = *(const half8*)&wp[ml * 8];
            half8 B1 = *(const half8*)&wp[(16 + ml) * 8];
            uint4 eA = *(const uint4*)&epc[k * 16];      // L2 broadcast (16-lane dup)
            uint4 fA = *(const uint4*)&fpc[k * 16];
            unsigned st = mw[k] >> (q * 8);
            union { unsigned u[4]; half8 s; } f0;
            const unsigned* ea = &eA.x;
            const unsigned* fa = &fA.x;
            #pragma unroll
            for (int pp = 0; pp < 4; ++pp) {
                union { unsigned u; h2 h; } uE, uF, uP;
                uE.u = ea[pp]; uF.u = fa[pp];
                uP.h = __builtin_elementwise_max(uF.h * gi2, uE.h);
                unsigned mA = (unsigned)__builtin_amdgcn_sbfe(st, 2 * pp, 1);
                unsigned mB = (unsigned)__builtin_amdgcn_sbfe(st, 2 * pp + 1, 1);
                unsigned m32 = __builtin_amdgcn_perm(mB, mA, 0x05040100u);
                f0.u[pp] = uP.u & m32;
            }
            accP = __builtin_amdgcn_mfma_f32_16x16x32_f16(f0.s, B0, accP, 0, 0, 0);
            accQ = __builtin_amdgcn_mfma_f32_16x16x32_f16(f0.s, B1, accQ, 0, 0, 0);
            accD = __builtin_amdgcn_mfma_f32_16x16x32_f16(f0.s, hones, accD, 0, 0, 0);
        }
    }

    // combine js halves: reuse whs (13.3KB needed, 32KB available)
    __syncthreads();                      // all compute done; whs reusable
    float* cmb = (float*)&whs[0][0][0];   // [rw*64+l][13]
    float* myc = &cmb[(rw * 64 + l) * 13];
    if (js == 1) {
        *(f32x4*)&myc[0] = accP;
        *(f32x4*)&myc[4] = accQ;
        *(f32x4*)&myc[8] = accD;
    }
    __syncthreads();
    if (js == 0) {
        f32x4 oP = *(const f32x4*)&myc[0];
        f32x4 oQ = *(const f32x4*)&myc[4];
        f32x4 oD = *(const f32x4*)&myc[8];
        #pragma unroll
        for (int r = 0; r < 4; ++r) {
            int ir = i0 + q * 4 + r;
            float inv = 1.0f / (accD[r] + oD[r]);
            size_t ba = ((size_t)(b * NN + ir)) * (HH * DD) + h * DD;
            out[ba + ml]      = (accP[r] + oP[r]) * inv;
            out[ba + 16 + ml] = (accQ[r] + oQ[r]) * inv;
        }
    }
}

extern "C" void kernel_launch(void* const* d_in, const int* in_sizes, int n_in,
                              void* d_out, int out_size, void* d_ws, size_t ws_size,
                              hipStream_t stream) {
    (void)in_sizes; (void)n_in; (void)out_size; (void)ws_size;
    const float* x   = (const float*)d_in[0];
    const int*   adj = (const int*)d_in[1];
    const float* W   = (const float*)d_in[2];
    const float* a   = (const float*)d_in[3];
    float* out = (float*)d_out;

    char* ws = (char*)d_ws;
    unsigned short* whT2 = (unsigned short*)ws;                          // 4 MB
    float*    esrc  = (float*)(ws + (4u << 20));                         // 256 KB
    unsigned* ejE   = (unsigned*)(ws + (4u << 20) + (256u << 10));       // 128 KB
    unsigned* ejF   = (unsigned*)(ws + (4u << 20) + (384u << 10));       // 128 KB
    unsigned* bitsG = (unsigned*)(ws + (4u << 20) + (512u << 10));       // 2 MB
    float*    we_g  = (float*)(ws + (4u << 20) + (512u << 10) + (2u << 20)); // 16 KB
    unsigned short* wTf16 = (unsigned short*)(ws + (4u << 20) + (512u << 10)
                                              + (2u << 20) + (16u << 10));   // 128 KB

    adjprep_kernel<<<dim3(2080), dim3(256), 0, stream>>>(adj, W, a, bitsG, we_g, wTf16);
    prepw_kernel  <<<dim3(1024), dim3(256), 0, stream>>>(x, wTf16, we_g, whT2, esrc, ejE, ejF);
    attn_kernel   <<<dim3(1024), dim3(512), 0, stream>>>(whT2, esrc, ejE, ejF, bitsG, out);
}

// Round 16
// 140.699 us; speedup vs baseline: 1.0409x; 1.0409x over previous
//
#include <hip/hip_runtime.h>

#define BB 4
#define NN 2048
#define INF 256
#define HH 8
#define DD 32
#define LOG2E 1.4426950408889634f

typedef __attribute__((ext_vector_type(8))) _Float16 half8;
typedef __attribute__((ext_vector_type(8))) short short8;
typedef __attribute__((ext_vector_type(2))) _Float16 h2;
typedef __attribute__((ext_vector_type(4))) float f32x4;
typedef __attribute__((address_space(3))) unsigned as3_u32;
typedef __attribute__((address_space(1))) const unsigned as1_u32;

__device__ __forceinline__ unsigned short f16u(float v) {
    union { _Float16 f; unsigned short u; } c;
    c.f = (_Float16)v;
    return c.u;
}

// adjprep: zero-LDS. bid<2048: adjbits (1 row/wave, 32 loads in flight, ballots
// on regs, one coalesced 256B store). bid>=2048 (32 blocks): wprep — wTf16
// [h*32+d][f] f16 transpose of W (computed once, not per-whk-block) + we dots.
__global__ __launch_bounds__(256) void adjprep_kernel(
    const int* __restrict__ adj, const float* __restrict__ W,
    const float* __restrict__ a, unsigned* __restrict__ bitsG,
    float* __restrict__ we_g, unsigned short* __restrict__ wTf16)
{
    const int bid = blockIdx.x, t = threadIdx.x;
    if (bid < 2048) {
        const int wv = t >> 6, l = t & 63;
        const int row = bid * 4 + wv;                   // global (b*N + i) row
        const int* ap = adj + (size_t)row * NN;
        int vreg[32];
        #pragma unroll
        for (int c = 0; c < 32; ++c) vreg[c] = ap[c * 64 + l];   // 32 in flight
        unsigned myw = 0;
        #pragma unroll
        for (int c = 0; c < 32; ++c) {
            unsigned long long m = __ballot(vreg[c] != 0);
            unsigned sel = (l & 1) ? (unsigned)(m >> 32) : (unsigned)m;
            myw = ((l >> 1) == c) ? sel : myw;
        }
        bitsG[(size_t)row * 64 + l] = myw;              // 256B coalesced
        return;
    }
    const int k = bid - 2048;                           // 0..31
    if (k < 16) {                                       // we part
        const int h = k & 7, sel = k >> 3;
        const float* wr = W + ((size_t)(h * INF + t)) * DD;
        const float* av = a + h * 2 * DD + sel * DD;
        float acc = 0.f;
        #pragma unroll
        for (int d = 0; d < DD; ++d) acc += wr[d] * av[d];
        we_g[k * INF + t] = acc * LOG2E;
    }
    #pragma unroll
    for (int r2 = 0; r2 < 8; ++r2) {                    // wT rows k*8 .. k*8+8
        int row = k * 8 + r2;
        int h = row >> 5, d = row & 31;
        wTf16[row * INF + t] = f16u(W[((size_t)(h * INF + t)) * DD + d]);
    }
}

// prepw: role = bid&1.
// role0 (512): whk GEMM — x staged coalesced->f16 LDS; wb staged from wTf16
//   (coalesced short8, no per-block transpose). -> whT2 f16 [bh][j/8][d][8].
// role1 (512): ek — xs+weld2 staged; -> esrc (log2 fp32) + ejE/ejF f16 pairs.
__global__ __launch_bounds__(256) void prepw_kernel(
    const float* __restrict__ x, const unsigned short* __restrict__ wTf16,
    const float* __restrict__ we_g, unsigned short* __restrict__ whT2,
    float* __restrict__ esrc, unsigned* __restrict__ ejE,
    unsigned* __restrict__ ejF)
{
    __shared__ __align__(16) unsigned short smem[64 * 264 * 2];
    const int bid = blockIdx.x, t = threadIdx.x;
    const int role = bid & 1, id = bid >> 1;

    if (role == 0) {                       // ---- whk ----
        unsigned short* xb = smem;                       // [64][264] f16
        unsigned short* wb = smem + 64 * 264;            // [64][264] f16
        const int hp = id & 3, tl = (id >> 2) & 31, b = id >> 7;
        const int n0 = tl * 64;

        #pragma unroll
        for (int p = 0; p < 16; ++p) {                   // x tile -> f16 LDS
            int flat = p * 1024 + t * 4;
            int row = flat >> 8, col = flat & 255;
            f32x4 g = *(const f32x4*)&x[((size_t)(b * NN + n0 + row)) * INF + col];
            union { h2 h; unsigned u; } c0, c1;
            c0.h = (h2){(_Float16)g[0], (_Float16)g[1]};
            c1.h = (h2){(_Float16)g[2], (_Float16)g[3]};
            uint2 pk; pk.x = c0.u; pk.y = c1.u;
            *(uint2*)&xb[row * 264 + col] = pk;
        }
        #pragma unroll
        for (int p = 0; p < 8; ++p) {                    // wb from wTf16: coalesced
            int flat = p * 2048 + t * 8;                 // 8 halfs (16B) per thread
            int row = flat >> 8, col = flat & 255;
            short8 v = *(const short8*)&wTf16[(size_t)(hp * 64 + row) * INF + col];
            *(short8*)&wb[row * 264 + col] = v;
        }
        __syncthreads();

        const int w = t >> 6, l = t & 63;
        const int ml = l & 15, q = l >> 4;
        f32x4 acc[4] = {};
        const unsigned short* apx = &xb[(w * 16 + ml) * 264 + q * 8];
        #pragma unroll
        for (int k0 = 0; k0 < INF; k0 += 32) {
            half8 A = *(const half8*)&apx[k0];
            #pragma unroll
            for (int c16 = 0; c16 < 4; ++c16) {
                half8 Bf = *(const half8*)&wb[(c16 * 16 + ml) * 264 + q * 8 + k0];
                acc[c16] = __builtin_amdgcn_mfma_f32_16x16x32_f16(A, Bf, acc[c16], 0, 0, 0);
            }
        }
        __syncthreads();
        unsigned short* ldsC = xb;                       // [64 col][72 row]
        #pragma unroll
        for (int c16 = 0; c16 < 4; ++c16)
            #pragma unroll
            for (int r = 0; r < 4; ++r) {
                int col = c16 * 16 + ml;
                int rt  = w * 16 + q * 4 + r;
                ldsC[col * 72 + rt] = f16u(acc[c16][r]);
            }
        __syncthreads();
        #pragma unroll
        for (int p = 0; p < 2; ++p) {
            int g = p * 256 + t;
            int d = g & 31, jo = (g >> 5) & 7, hh = g >> 8;
            half8 vv = *(const half8*)&ldsC[(hh * 32 + d) * 72 + jo * 8];
            int bh = b * 8 + hp * 2 + hh;
            *(half8*)&whT2[(((size_t)bh * 256 + tl * 8 + jo) * 32 + d) * 8] = vv;
        }
        return;
    }

    // ---- ek ----
    float* xs    = (float*)smem;                         // [16][260]
    float* weld2 = (float*)smem + 16 * 260;              // [c=f>>4][k*16+fi]
    const int tile = id & 127, b = id >> 7;
    const int n0 = tile * 16;

    #pragma unroll
    for (int p = 0; p < 4; ++p) {
        int flat = p * 1024 + t * 4;
        int row = flat >> 8, col = flat & 255;
        f32x4 g = *(const f32x4*)&x[((size_t)(b * NN + n0 + row)) * INF + col];
        *(f32x4*)&xs[row * 260 + col] = g;
    }
    #pragma unroll
    for (int p = 0; p < 4; ++p) {                        // we_g: 4096 floats
        int flat = p * 1024 + t * 4;
        int k = flat >> 8, f = flat & 255;
        f32x4 g = *(const f32x4*)&we_g[flat];
        *(f32x4*)&weld2[(f >> 4) * 260 + k * 16 + (f & 15)] = g;
    }
    __syncthreads();

    const int row = t >> 4, cc = t & 15;
    f32x4 xv[4];
    #pragma unroll
    for (int i = 0; i < 4; ++i)
        xv[i] = *(const f32x4*)&xs[row * 260 + cc * 16 + i * 4];

    float keep = 0.f;
    #pragma unroll
    for (int k = 0; k < 16; ++k) {
        float s = 0.f;
        #pragma unroll
        for (int i = 0; i < 4; ++i) {
            f32x4 w4 = *(const f32x4*)&weld2[cc * 260 + k * 16 + i * 4];
            s += xv[i][0]*w4[0] + xv[i][1]*w4[1] + xv[i][2]*w4[2] + xv[i][3]*w4[3];
        }
        s += __shfl_xor(s, 1, 64);
        s += __shfl_xor(s, 2, 64);
        s += __shfl_xor(s, 4, 64);
        s += __shfl_xor(s, 8, 64);
        keep = (cc == k) ? s : keep;
    }
    const int n = n0 + row;
    // all lanes compute + shfl (uniform exec); only cc>=8 even rows store
    float Ej = __builtin_amdgcn_exp2f(keep);
    float Fj = __builtin_amdgcn_exp2f(0.2f * keep);
    unsigned eh = (unsigned)f16u(Ej);
    unsigned fh = (unsigned)f16u(Fj);
    unsigned eo = (unsigned)__shfl_xor((int)eh, 16, 64);  // partner row (n^1)
    unsigned fo = (unsigned)__shfl_xor((int)fh, 16, 64);
    if (cc < 8) {
        esrc[(b * 8 + cc) * NN + n] = keep;
    } else if (!(row & 1)) {
        int bh = b * 8 + (cc - 8);
        ejE[bh * 1024 + n / 2] = (eo << 16) | eh;
        ejF[bh * 1024 + n / 2] = (fo << 16) | fh;
    }
}

// attn: 1024 blocks x 512 thr; 8 waves = 4 row-waves x 2 j-halves (js).
// Wave = 16 rows x 1024 j (8 chunk-iters). Per iter: stage whb chunks (2x8KB,
// dbuf) + paired E/F words; 1 barrier. Packed-f16 score math:
// p_pair = pk_max(pk_mul(F_pair, Gi2), E_pair) & mask32 — 6 VALU / 2 entries.
// Gi = 2^(-0.8 ei): per-row scale cancels in softmax. Combine js at the end.
__global__ __launch_bounds__(512, 8) void attn_kernel(
    const unsigned short* __restrict__ whT2, const float* __restrict__ esrc,
    const unsigned* __restrict__ ejE, const unsigned* __restrict__ ejF,
    const unsigned* __restrict__ bitsG, float* __restrict__ out)
{
    __shared__ __align__(16) unsigned short whs[2][2][4096];  // [buf][js][8KB]
    __shared__ __align__(16) unsigned epsE[2][2][64];         // [buf][js][64 pairs]
    __shared__ __align__(16) unsigned epsF[2][2][64];
    const int t = threadIdx.x, w = t >> 6, l = t & 63;
    const int rw = w & 3, js = w >> 2;
    const int ml = l & 15, q = l >> 4;
    const int obid = blockIdx.x;
    const int bid = (obid & 7) * 128 + (obid >> 3);         // XCD swizzle (1024=8*128)
    const int ig = bid & 31, h = (bid >> 5) & 7, b = bid >> 8;
    const int bh = b * HH + h;
    const int i0 = ig * 64 + rw * 16;                       // wave's 16 rows

    const float ei = esrc[bh * NN + i0 + ml];
    const float Gi = __builtin_amdgcn_exp2f(-0.8f * ei);
    const h2 gi2 = {(_Float16)Gi, (_Float16)Gi};

    const unsigned short* whb = whT2 + (size_t)bh * (256 * 256);  // [jg][d][8]
    const unsigned* epE = ejE + bh * 1024;
    const unsigned* epF = ejF + bh * 1024;
    const unsigned* mbase = bitsG + ((size_t)(b * NN + i0 + ml)) * 64 + js * 32;

    auto stage = [&](int it, int buf) {
        // this js-group's chunk (js*8+it): 8KB; wave rw stages bytes rw*2048..+2048
        const char* g = (const char*)whb + (js * 8 + it) * 8192 + rw * 2048 + l * 16;
        unsigned short* ld = &whs[buf][js][rw * 1024];        // wave-uniform base
        __builtin_amdgcn_global_load_lds((as1_u32*)g, (as3_u32*)ld, 16, 0, 0);
        __builtin_amdgcn_global_load_lds((as1_u32*)(g + 1024), (as3_u32*)(ld + 512), 16, 0, 0);
        if (rw == 0) {                                        // E/F pairs: 256B each
            __builtin_amdgcn_global_load_lds((as1_u32*)(epE + (js * 8 + it) * 64 + l),
                                             (as3_u32*)&epsE[buf][js][0], 4, 0, 0);
            __builtin_amdgcn_global_load_lds((as1_u32*)(epF + (js * 8 + it) * 64 + l),
                                             (as3_u32*)&epsF[buf][js][0], 4, 0, 0);
        }
    };

    const half8 hones = {(_Float16)1.f, (_Float16)1.f, (_Float16)1.f, (_Float16)1.f,
                         (_Float16)1.f, (_Float16)1.f, (_Float16)1.f, (_Float16)1.f};
    f32x4 accP = {}, accQ = {}, accD = {};

    stage(0, 0);
    uint4 mrow = *(const uint4*)&mbase[0];
    for (int it = 0; it < 8; ++it) {
        __syncthreads();                  // stage(it) complete; buf^1 free
        if (it < 7) stage(it + 1, (it + 1) & 1);
        const int buf = it & 1;
        const uint4 mcur = mrow;
        if (it < 7) mrow = *(const uint4*)&mbase[(it + 1) * 4];  // prefetch
        const unsigned mw[4] = {mcur.x, mcur.y, mcur.z, mcur.w};
        #pragma unroll
        for (int k = 0; k < 4; ++k) {
            const unsigned short* wp = &whs[buf][js][(k * 4 + q) * 256];
            half8 B0 = *(const half8*)&wp[ml * 8];
            half8 B1 = *(const half8*)&wp[(16 + ml) * 8];
            uint4 eA = *(const uint4*)&epsE[buf][js][k * 16 + q * 4];
            uint4 fA = *(const uint4*)&epsF[buf][js][k * 16 + q * 4];
            unsigned st = mw[k] >> (q * 8);
            union { unsigned u[4]; half8 s; } f0;
            const unsigned* ea = &eA.x;
            const unsigned* fa = &fA.x;
            #pragma unroll
            for (int pp = 0; pp < 4; ++pp) {
                union { unsigned u; h2 h; } uE, uF, uP;
                uE.u = ea[pp]; uF.u = fa[pp];
                uP.h = __builtin_elementwise_max(uF.h * gi2, uE.h);
                unsigned mA = (unsigned)__builtin_amdgcn_sbfe(st, 2 * pp, 1);
                unsigned mB = (unsigned)__builtin_amdgcn_sbfe(st, 2 * pp + 1, 1);
                unsigned m32 = __builtin_amdgcn_perm(mB, mA, 0x05040100u);
                f0.u[pp] = uP.u & m32;
            }
            accP = __builtin_amdgcn_mfma_f32_16x16x32_f16(f0.s, B0, accP, 0, 0, 0);
            accQ = __builtin_amdgcn_mfma_f32_16x16x32_f16(f0.s, B1, accQ, 0, 0, 0);
            accD = __builtin_amdgcn_mfma_f32_16x16x32_f16(f0.s, hones, accD, 0, 0, 0);
        }
    }

    // combine js halves: reuse whs (13.3KB needed, 32KB available)
    __syncthreads();                      // all compute done; whs reusable
    float* cmb = (float*)&whs[0][0][0];   // [rw*64+l][13]
    float* myc = &cmb[(rw * 64 + l) * 13];
    if (js == 1) {
        *(f32x4*)&myc[0] = accP;
        *(f32x4*)&myc[4] = accQ;
        *(f32x4*)&myc[8] = accD;
    }
    __syncthreads();
    if (js == 0) {
        f32x4 oP = *(const f32x4*)&myc[0];
        f32x4 oQ = *(const f32x4*)&myc[4];
        f32x4 oD = *(const f32x4*)&myc[8];
        #pragma unroll
        for (int r = 0; r < 4; ++r) {
            int ir = i0 + q * 4 + r;
            float inv = 1.0f / (accD[r] + oD[r]);
            size_t ba = ((size_t)(b * NN + ir)) * (HH * DD) + h * DD;
            out[ba + ml]      = (accP[r] + oP[r]) * inv;
            out[ba + 16 + ml] = (accQ[r] + oQ[r]) * inv;
        }
    }
}

extern "C" void kernel_launch(void* const* d_in, const int* in_sizes, int n_in,
                              void* d_out, int out_size, void* d_ws, size_t ws_size,
                              hipStream_t stream) {
    (void)in_sizes; (void)n_in; (void)out_size; (void)ws_size;
    const float* x   = (const float*)d_in[0];
    const int*   adj = (const int*)d_in[1];
    const float* W   = (const float*)d_in[2];
    const float* a   = (const float*)d_in[3];
    float* out = (float*)d_out;

    char* ws = (char*)d_ws;
    unsigned short* whT2 = (unsigned short*)ws;                          // 4 MB
    float*    esrc  = (float*)(ws + (4u << 20));                         // 256 KB
    unsigned* ejE   = (unsigned*)(ws + (4u << 20) + (256u << 10));       // 128 KB
    unsigned* ejF   = (unsigned*)(ws + (4u << 20) + (384u << 10));       // 128 KB
    unsigned* bitsG = (unsigned*)(ws + (4u << 20) + (512u << 10));       // 2 MB
    float*    we_g  = (float*)(ws + (4u << 20) + (512u << 10) + (2u << 20)); // 16 KB
    unsigned short* wTf16 = (unsigned short*)(ws + (4u << 20) + (512u << 10)
                                              + (2u << 20) + (16u << 10));   // 128 KB

    adjprep_kernel<<<dim3(2080), dim3(256), 0, stream>>>(adj, W, a, bitsG, we_g, wTf16);
    prepw_kernel  <<<dim3(1024), dim3(256), 0, stream>>>(x, wTf16, we_g, whT2, esrc, ejE, ejF);
    attn_kernel   <<<dim3(1024), dim3(512), 0, stream>>>(whT2, esrc, ejE, ejF, bitsG, out);
}